// Round 1
// baseline (448.523 us; speedup 1.0000x reference)
//
#include <hip/hip_runtime.h>
#include <math.h>

#define BB 8
#define TT 8192
#define XX 64
#define HH 128
#define CHUNK 32
#define NC (TT/CHUNK)

__device__ __forceinline__ float sigm(float x){ return 1.0f/(1.0f+__expf(-x)); }

// K1: embed (64->128) + leaky_relu + LN0.  block=128 (one thread per output col d),
// 32 rows per block in 4 octets of 8.
__global__ __launch_bounds__(128) void embed_kernel(
    const float* __restrict__ x, const float* __restrict__ ew, const float* __restrict__ eb,
    const float* __restrict__ g, const float* __restrict__ be, float* __restrict__ hout)
{
  __shared__ float xl[XX*8];
  __shared__ float red[2][16];
  int d = threadIdx.x;
  float bias = eb[d], gam = g[d], bet = be[d];
  for (int oc = 0; oc < 4; ++oc) {
    long row0 = (long)blockIdx.x*32 + oc*8;
    __syncthreads();
    #pragma unroll
    for (int j = 0; j < 4; ++j) {
      int f = d + j*128;
      int r = f >> 6, k = f & 63;
      xl[k*8 + r] = x[row0*XX + f];
    }
    __syncthreads();
    float acc[8];
    #pragma unroll
    for (int i = 0; i < 8; ++i) acc[i] = 0.f;
    #pragma unroll 2
    for (int k = 0; k < XX; ++k) {
      float wv = ew[k*HH + d];
      float4 a0 = *reinterpret_cast<const float4*>(&xl[k*8]);
      float4 a1 = *reinterpret_cast<const float4*>(&xl[k*8+4]);
      acc[0]+=a0.x*wv; acc[1]+=a0.y*wv; acc[2]+=a0.z*wv; acc[3]+=a0.w*wv;
      acc[4]+=a1.x*wv; acc[5]+=a1.y*wv; acc[6]+=a1.z*wv; acc[7]+=a1.w*wv;
    }
    float s[8], q[8];
    #pragma unroll
    for (int r = 0; r < 8; ++r) {
      float v = acc[r] + bias;
      v = v > 0.f ? v : 0.01f*v;
      acc[r] = v; s[r] = v; q[r] = v*v;
    }
    #pragma unroll
    for (int m = 1; m < 64; m <<= 1) {
      #pragma unroll
      for (int r = 0; r < 8; ++r) {
        s[r] += __shfl_xor(s[r], m);
        q[r] += __shfl_xor(q[r], m);
      }
    }
    int wid = d >> 6;
    if ((d & 63) == 0) {
      #pragma unroll
      for (int r = 0; r < 8; ++r) { red[wid][r*2] = s[r]; red[wid][r*2+1] = q[r]; }
    }
    __syncthreads();
    #pragma unroll
    for (int r = 0; r < 8; ++r) {
      float st = red[0][r*2] + red[1][r*2];
      float qt = red[0][r*2+1] + red[1][r*2+1];
      float mu = st * (1.f/128.f);
      float var = qt * (1.f/128.f) - mu*mu;
      float rs = rsqrtf(var + 1e-5f);
      hout[(row0+r)*HH + d] = (acc[r]-mu)*rs*gam + bet;
    }
  }
}

// K2: hg = h @ W(128x256) + b for one (batch, 32-t chunk); thread d owns hidden col d
// AND gate col d+128 -> computes a = 1-z, bb = z*g(hidden) locally, stores them, and
// composes the chunk summary (A,B) in-register.
__global__ __launch_bounds__(128) void gru_matmul_kernel(
    const float* __restrict__ hin, const float* __restrict__ w, const float* __restrict__ bias,
    float* __restrict__ a_arr, float* __restrict__ b_arr,
    float* __restrict__ Asum, float* __restrict__ Bsum)
{
  __shared__ float hl[HH*20];
  int blk = blockIdx.x;
  int b = blk / NC, c = blk % NC;
  int t0 = c*CHUNK;
  int d = threadIdx.x;
  float bh = bias[d], bg = bias[HH+d];
  float A_run = 1.0f, B_run = 0.0f;
  const float* hbase = hin + ((long)b*TT + t0)*HH;
  for (int tg = 0; tg < CHUNK/16; ++tg) {
    __syncthreads();
    const float* src = hbase + tg*16*HH;
    #pragma unroll
    for (int j = 0; j < 16; ++j) hl[d*20 + j] = src[j*HH + d];
    __syncthreads();
    float acch[16], accg[16];
    #pragma unroll
    for (int i = 0; i < 16; ++i) { acch[i]=0.f; accg[i]=0.f; }
    #pragma unroll 2
    for (int k = 0; k < HH; ++k) {
      float wh = w[(k<<8) + d];
      float wg = w[(k<<8) + HH + d];
      const float4* hv = reinterpret_cast<const float4*>(&hl[k*20]);
      float4 v0 = hv[0], v1 = hv[1], v2 = hv[2], v3 = hv[3];
      acch[0]+=v0.x*wh; accg[0]+=v0.x*wg;
      acch[1]+=v0.y*wh; accg[1]+=v0.y*wg;
      acch[2]+=v0.z*wh; accg[2]+=v0.z*wg;
      acch[3]+=v0.w*wh; accg[3]+=v0.w*wg;
      acch[4]+=v1.x*wh; accg[4]+=v1.x*wg;
      acch[5]+=v1.y*wh; accg[5]+=v1.y*wg;
      acch[6]+=v1.z*wh; accg[6]+=v1.z*wg;
      acch[7]+=v1.w*wh; accg[7]+=v1.w*wg;
      acch[8]+=v2.x*wh; accg[8]+=v2.x*wg;
      acch[9]+=v2.y*wh; accg[9]+=v2.y*wg;
      acch[10]+=v2.z*wh; accg[10]+=v2.z*wg;
      acch[11]+=v2.w*wh; accg[11]+=v2.w*wg;
      acch[12]+=v3.x*wh; accg[12]+=v3.x*wg;
      acch[13]+=v3.y*wh; accg[13]+=v3.y*wg;
      acch[14]+=v3.z*wh; accg[14]+=v3.z*wg;
      acch[15]+=v3.w*wh; accg[15]+=v3.w*wg;
    }
    long obase = ((long)b*TT + t0 + tg*16)*HH + d;
    #pragma unroll
    for (int i = 0; i < 16; ++i) {
      float hid = acch[i] + bh;
      float z = sigm(accg[i] + bg);
      float gv = hid >= 0.f ? hid + 0.5f : sigm(hid);
      float av = 1.f - z;
      float bv = z * gv;
      a_arr[obase + (long)i*HH] = av;
      b_arr[obase + (long)i*HH] = bv;
      A_run *= av;
      B_run = av*B_run + bv;
    }
  }
  int sidx = (b*NC + c)*HH + d;
  Asum[sidx] = A_run;
  Bsum[sidx] = B_run;
}

// K3: serial scan over the 256 chunk summaries per (b,d); carry[c] = h before chunk c.
__global__ __launch_bounds__(128) void scan_kernel(
    const float* __restrict__ Asum, const float* __restrict__ Bsum, float* __restrict__ carry)
{
  int b = blockIdx.x; int d = threadIdx.x;
  float run = 0.f;
  #pragma unroll 4
  for (int c = 0; c < NC; ++c) {
    int idx = (b*NC + c)*HH + d;
    carry[idx] = run;
    run = Asum[idx]*run + Bsum[idx];
  }
}

// K4: apply recurrence within chunk + fused LayerNorm.  64 threads, 2 channels per lane,
// in-wave shuffle reduction for mean/var (no barriers).
__global__ __launch_bounds__(64) void apply_kernel(
    const float* __restrict__ a_arr, const float* __restrict__ b_arr, const float* __restrict__ carry,
    const float* __restrict__ g, const float* __restrict__ be, float* __restrict__ hout)
{
  int blk = blockIdx.x; int b = blk/NC, c = blk%NC;
  int lane = threadIdx.x;
  float2 h = reinterpret_cast<const float2*>(carry + (long)(b*NC+c)*HH)[lane];
  float2 gam = reinterpret_cast<const float2*>(g)[lane];
  float2 bet = reinterpret_cast<const float2*>(be)[lane];
  long base = ((long)b*TT + (long)c*CHUNK)*HH;
  for (int t = 0; t < CHUNK; ++t) {
    float2 av = reinterpret_cast<const float2*>(a_arr + base + t*HH)[lane];
    float2 bv = reinterpret_cast<const float2*>(b_arr + base + t*HH)[lane];
    h.x = av.x*h.x + bv.x;
    h.y = av.y*h.y + bv.y;
    float s = h.x + h.y, q = h.x*h.x + h.y*h.y;
    #pragma unroll
    for (int m = 1; m < 64; m <<= 1) { s += __shfl_xor(s, m); q += __shfl_xor(q, m); }
    float mu = s * (1.f/128.f);
    float var = q * (1.f/128.f) - mu*mu;
    float rs = rsqrtf(var + 1e-5f);
    float2 o;
    o.x = (h.x-mu)*rs*gam.x + bet.x;
    o.y = (h.y-mu)*rs*gam.y + bet.y;
    reinterpret_cast<float2*>(hout + base + t*HH)[lane] = o;
  }
}

// K5: proj (128->50) + softplus.  256 threads = 4 teams of 64 lanes; team handles 8 rows.
__global__ __launch_bounds__(256) void proj_kernel(
    const float* __restrict__ hin, const float* __restrict__ pw, const float* __restrict__ pb,
    float* __restrict__ out)
{
  __shared__ float hl[4][HH*8];
  int tid = threadIdx.x;
  int tm = tid >> 6, lane = tid & 63;
  long row0 = (long)blockIdx.x*32 + tm*8;
  #pragma unroll
  for (int j = 0; j < 16; ++j) {
    int f = lane + j*64;
    int r = f >> 7, k = f & 127;
    hl[tm][k*8 + r] = hin[row0*HH + f];
  }
  __syncthreads();
  float acc[8];
  #pragma unroll
  for (int i = 0; i < 8; ++i) acc[i] = 0.f;
  bool act = lane < 50;
  #pragma unroll 2
  for (int k = 0; k < HH; ++k) {
    float wv = act ? pw[k*50 + lane] : 0.f;
    float4 a0 = *reinterpret_cast<const float4*>(&hl[tm][k*8]);
    float4 a1 = *reinterpret_cast<const float4*>(&hl[tm][k*8+4]);
    acc[0]+=a0.x*wv; acc[1]+=a0.y*wv; acc[2]+=a0.z*wv; acc[3]+=a0.w*wv;
    acc[4]+=a1.x*wv; acc[5]+=a1.y*wv; acc[6]+=a1.z*wv; acc[7]+=a1.w*wv;
  }
  if (act) {
    float bias = pb[lane];
    #pragma unroll
    for (int r = 0; r < 8; ++r) {
      float v = acc[r] + bias;
      float sp = fmaxf(v, 0.f) + log1pf(__expf(-fabsf(v)));
      out[(row0+r)*50 + lane] = sp;
    }
  }
}

extern "C" void kernel_launch(void* const* d_in, const int* in_sizes, int n_in,
                              void* d_out, int out_size, void* d_ws, size_t ws_size,
                              hipStream_t stream) {
  const float* x    = (const float*)d_in[0];
  const float* ew   = (const float*)d_in[1];
  const float* eb   = (const float*)d_in[2];
  const float* ln0g = (const float*)d_in[3];
  const float* ln0b = (const float*)d_in[4];
  const float* pw   = (const float*)d_in[5];
  const float* pb   = (const float*)d_in[6];
  float* out = (float*)d_out;

  float* ws = (float*)d_ws;
  size_t nBT = (size_t)BB*TT*HH;        // 8.39M floats
  size_t nSum = (size_t)BB*NC*HH;       // 262144 floats
  float* h     = ws;
  float* a_arr = h + nBT;
  float* b_arr = a_arr + nBT;
  float* Asum  = b_arr + nBT;
  float* Bsum  = Asum + nSum;
  float* carry = Bsum + nSum;

  embed_kernel<<<(BB*TT)/32, 128, 0, stream>>>(x, ew, eb, ln0g, ln0b, h);

  for (int l = 0; l < 3; ++l) {
    const float* gw = (const float*)d_in[7 + 4*l];
    const float* gb = (const float*)d_in[8 + 4*l];
    const float* lg = (const float*)d_in[9 + 4*l];
    const float* lb = (const float*)d_in[10 + 4*l];
    gru_matmul_kernel<<<BB*NC, 128, 0, stream>>>(h, gw, gb, a_arr, b_arr, Asum, Bsum);
    scan_kernel<<<BB, 128, 0, stream>>>(Asum, Bsum, carry);
    apply_kernel<<<BB*NC, 64, 0, stream>>>(a_arr, b_arr, carry, lg, lb, h);
  }

  proj_kernel<<<(BB*TT)/32, 256, 0, stream>>>(h, pw, pb, out);
}

// Round 2
// 292.049 us; speedup vs baseline: 1.5358x; 1.5358x over previous
//
#include <hip/hip_runtime.h>
#include <math.h>

#define BB 8
#define TT 8192
#define XX 64
#define HH 128
#define CHUNK 32
#define NC (TT/CHUNK)

typedef __attribute__((ext_vector_type(8))) short short8;
typedef __attribute__((ext_vector_type(4))) float f32x4;

__device__ __forceinline__ float sigm(float x){ return 1.0f/(1.0f+__expf(-x)); }
__device__ __forceinline__ unsigned short f2bf(float f){
  unsigned u = __float_as_uint(f);
  return (unsigned short)((u + 0x7fffu + ((u>>16)&1u)) >> 16);
}
__device__ __forceinline__ float bf2f(unsigned b){ return __uint_as_float(b << 16); }

// P0: transpose+convert gru weights (128x256 f32) -> wt[l][col][k] bf16, PRE-SWIZZLED
// (byte ^= (col&7)<<4) so the mm kernel can stage LDS linearly and ds_read with the
// same XOR -> conflict-free ds_read_b128.
__global__ __launch_bounds__(256) void prep_kernel(
    const float* __restrict__ w1, const float* __restrict__ w2, const float* __restrict__ w3,
    unsigned short* __restrict__ wt)
{
  int idx = blockIdx.x*256 + threadIdx.x;       // 0 .. 3*32768-1
  int l = idx >> 15;
  int e = idx & 32767;
  int k = e >> 8;                               // 0..127
  int col = e & 255;                            // 0..255
  const float* w = (l==0) ? w1 : ((l==1) ? w2 : w3);
  float v = w[e];
  unsigned byte = ((unsigned)col*128u + (unsigned)k)*2u;
  byte ^= (unsigned)((col & 7) << 4);
  wt[(size_t)l*32768 + (byte >> 1)] = f2bf(v);
}

// K1: embed (64->128) + leaky_relu + LN0 -> h (bf16)
__global__ __launch_bounds__(128) void embed_kernel(
    const float* __restrict__ x, const float* __restrict__ ew, const float* __restrict__ eb,
    const float* __restrict__ g, const float* __restrict__ be, unsigned short* __restrict__ hout)
{
  __shared__ float xl[XX*8];
  __shared__ float red[2][16];
  int d = threadIdx.x;
  float bias = eb[d], gam = g[d], bet = be[d];
  for (int oc = 0; oc < 4; ++oc) {
    long row0 = (long)blockIdx.x*32 + oc*8;
    __syncthreads();
    #pragma unroll
    for (int j = 0; j < 4; ++j) {
      int f = d + j*128;
      int r = f >> 6, k = f & 63;
      xl[k*8 + r] = x[row0*XX + f];
    }
    __syncthreads();
    float acc[8];
    #pragma unroll
    for (int i = 0; i < 8; ++i) acc[i] = 0.f;
    #pragma unroll 2
    for (int k = 0; k < XX; ++k) {
      float wv = ew[k*HH + d];
      float4 a0 = *reinterpret_cast<const float4*>(&xl[k*8]);
      float4 a1 = *reinterpret_cast<const float4*>(&xl[k*8+4]);
      acc[0]+=a0.x*wv; acc[1]+=a0.y*wv; acc[2]+=a0.z*wv; acc[3]+=a0.w*wv;
      acc[4]+=a1.x*wv; acc[5]+=a1.y*wv; acc[6]+=a1.z*wv; acc[7]+=a1.w*wv;
    }
    float s[8], q[8];
    #pragma unroll
    for (int r = 0; r < 8; ++r) {
      float v = acc[r] + bias;
      v = v > 0.f ? v : 0.01f*v;
      acc[r] = v; s[r] = v; q[r] = v*v;
    }
    #pragma unroll
    for (int m = 1; m < 64; m <<= 1) {
      #pragma unroll
      for (int r = 0; r < 8; ++r) {
        s[r] += __shfl_xor(s[r], m);
        q[r] += __shfl_xor(q[r], m);
      }
    }
    int wid = d >> 6;
    if ((d & 63) == 0) {
      #pragma unroll
      for (int r = 0; r < 8; ++r) { red[wid][r*2] = s[r]; red[wid][r*2+1] = q[r]; }
    }
    __syncthreads();
    #pragma unroll
    for (int r = 0; r < 8; ++r) {
      float st = red[0][r*2] + red[1][r*2];
      float qt = red[0][r*2+1] + red[1][r*2+1];
      float mu = st * (1.f/128.f);
      float var = qt * (1.f/128.f) - mu*mu;
      float rs = rsqrtf(var + 1e-5f);
      hout[(row0+r)*HH + d] = f2bf((acc[r]-mu)*rs*gam + bet);
    }
  }
}

// K2: MFMA minGRU matmul. Block = 4 waves, wave = 1 chunk (32 rows).
// W^T bf16 staged to LDS (64KB, pre-swizzled source -> linear stage, XOR'd reads).
// Col-tile pair (np, np+8) = (hidden, gate) share lane positions -> local activations.
// Chunk summary (A,B) composed in-lane (4 rows) then 2-step shfl_up affine scan.
__global__ __launch_bounds__(256) void gru_mm_kernel(
    const unsigned short* __restrict__ h, const unsigned short* __restrict__ wt,
    const float* __restrict__ bias,
    unsigned* __restrict__ ab, float* __restrict__ Asum, float* __restrict__ Bsum)
{
  __shared__ short8 wlds[4096];   // 64 KB
  int tid = threadIdx.x;
  const short8* wsrc = (const short8*)wt;
  #pragma unroll
  for (int i = 0; i < 16; ++i) wlds[i*256 + tid] = wsrc[i*256 + tid];
  __syncthreads();

  int wid = tid >> 6, lane = tid & 63;
  int chunk = blockIdx.x*4 + wid;
  int b = chunk >> 8;            // NC = 256
  int c = chunk & 255;
  long row0 = (long)b*TT + (long)c*CHUNK;
  int lr = lane & 15, lg = lane >> 4;
  int sx = (lane & 7) << 4;

  // A fragments: 2 row-tiles x 4 k-steps, 16B/lane direct from global bf16 h
  short8 af[2][4];
  #pragma unroll
  for (int m = 0; m < 2; ++m)
    #pragma unroll
    for (int s = 0; s < 4; ++s)
      af[m][s] = *(const short8*)(h + (row0 + m*16 + lr)*HH + s*32 + lg*8);

  const char* wbase = (const char*)wlds;
  #pragma unroll 2
  for (int np = 0; np < 8; ++np) {
    f32x4 acch[2], accg[2];
    #pragma unroll
    for (int m = 0; m < 2; ++m) { acch[m] = (f32x4){0.f,0.f,0.f,0.f}; accg[m] = (f32x4){0.f,0.f,0.f,0.f}; }
    int rh = np*16 + lr;
    int rg = rh + 128;
    #pragma unroll
    for (int s = 0; s < 4; ++s) {
      short8 bh = *(const short8*)(wbase + ((rh*256 + s*64 + lg*16) ^ sx));
      short8 bg = *(const short8*)(wbase + ((rg*256 + s*64 + lg*16) ^ sx));
      #pragma unroll
      for (int m = 0; m < 2; ++m) {
        acch[m] = __builtin_amdgcn_mfma_f32_16x16x32_bf16(af[m][s], bh, acch[m], 0, 0, 0);
        accg[m] = __builtin_amdgcn_mfma_f32_16x16x32_bf16(af[m][s], bg, accg[m], 0, 0, 0);
      }
    }
    int col = np*16 + lr;
    float bh0 = bias[col], bg0 = bias[HH + col];
    float At[2], Bt[2];
    #pragma unroll
    for (int m = 0; m < 2; ++m) {
      float A4 = 1.f, B4 = 0.f;
      #pragma unroll
      for (int r = 0; r < 4; ++r) {
        float hid = acch[m][r] + bh0;
        float z = sigm(accg[m][r] + bg0);
        float gv = hid >= 0.f ? hid + 0.5f : sigm(hid);
        float av = 1.f - z, bv = z*gv;
        size_t grow = (size_t)(row0 + m*16 + lg*4 + r);
        ab[grow*HH + col] = (unsigned)f2bf(av) | ((unsigned)f2bf(bv) << 16);
        A4 *= av; B4 = av*B4 + bv;
      }
      #pragma unroll
      for (int off = 1; off < 4; off <<= 1) {
        float pa = __shfl_up(A4, off*16);
        float pb = __shfl_up(B4, off*16);
        float na = pa*A4, nb = A4*pb + B4;
        if (lg >= off) { A4 = na; B4 = nb; }
      }
      At[m] = __shfl(A4, 48 + lr);
      Bt[m] = __shfl(B4, 48 + lr);
    }
    if (lane < 16) {
      float Ac = At[0]*At[1];
      float Bc = At[1]*Bt[0] + Bt[1];
      int sidx = chunk*HH + col;
      Asum[sidx] = Ac;
      Bsum[sidx] = Bc;
    }
  }
}

// K3: serial scan over 256 chunk summaries per (b,d)
__global__ __launch_bounds__(128) void scan_kernel(
    const float* __restrict__ Asum, const float* __restrict__ Bsum, float* __restrict__ carry)
{
  int b = blockIdx.x; int d = threadIdx.x;
  float run = 0.f;
  #pragma unroll 4
  for (int c = 0; c < NC; ++c) {
    int idx = (b*NC + c)*HH + d;
    carry[idx] = run;
    run = Asum[idx]*run + Bsum[idx];
  }
}

// K4: apply recurrence + fused LN -> h (bf16). Block = 4 waves, wave = 1 chunk.
// 8-timestep prefetch groups; uint2 loads (2 channels/lane, a+b packed).
__global__ __launch_bounds__(256) void apply_kernel(
    const unsigned* __restrict__ ab, const float* __restrict__ carry,
    const float* __restrict__ g, const float* __restrict__ be,
    unsigned short* __restrict__ hout)
{
  int tid = threadIdx.x, wid = tid >> 6, lane = tid & 63;
  int chunk = blockIdx.x*4 + wid;
  float2 hc = ((const float2*)(carry + (size_t)chunk*HH))[lane];
  float2 gam = ((const float2*)g)[lane];
  float2 bet = ((const float2*)be)[lane];
  size_t rowbase = (size_t)chunk*CHUNK;
  for (int gq = 0; gq < 4; ++gq) {
    uint2 v[8];
    #pragma unroll
    for (int j = 0; j < 8; ++j)
      v[j] = ((const uint2*)(ab + (rowbase + gq*8 + j)*HH))[lane];
    #pragma unroll
    for (int j = 0; j < 8; ++j) {
      float ax = bf2f(v[j].x & 0xffffu), bx = bf2f(v[j].x >> 16);
      float ay = bf2f(v[j].y & 0xffffu), by = bf2f(v[j].y >> 16);
      hc.x = ax*hc.x + bx;
      hc.y = ay*hc.y + by;
      float s = hc.x + hc.y, q = hc.x*hc.x + hc.y*hc.y;
      #pragma unroll
      for (int m = 1; m < 64; m <<= 1) { s += __shfl_xor(s, m); q += __shfl_xor(q, m); }
      float mu = s * (1.f/128.f);
      float var = q * (1.f/128.f) - mu*mu;
      float rs = rsqrtf(var + 1e-5f);
      unsigned o = (unsigned)f2bf((hc.x-mu)*rs*gam.x + bet.x)
                 | ((unsigned)f2bf((hc.y-mu)*rs*gam.y + bet.y) << 16);
      ((unsigned*)hout)[(rowbase + gq*8 + j)*64 + lane] = o;
    }
  }
}

// K5: proj (128->50) + softplus, bf16 input
__global__ __launch_bounds__(256) void proj_kernel(
    const unsigned short* __restrict__ hin, const float* __restrict__ pw, const float* __restrict__ pb,
    float* __restrict__ out)
{
  __shared__ float hl[4][HH*8];
  int tid = threadIdx.x;
  int tm = tid >> 6, lane = tid & 63;
  long row0 = (long)blockIdx.x*32 + tm*8;
  #pragma unroll
  for (int j = 0; j < 8; ++j) {
    unsigned v = *(const unsigned*)(hin + (row0 + j)*HH + lane*2);
    hl[tm][(lane*2)*8 + j]   = bf2f(v & 0xffffu);
    hl[tm][(lane*2+1)*8 + j] = bf2f(v >> 16);
  }
  __syncthreads();
  float acc[8];
  #pragma unroll
  for (int i = 0; i < 8; ++i) acc[i] = 0.f;
  bool act = lane < 50;
  #pragma unroll 2
  for (int k = 0; k < HH; ++k) {
    float wv = act ? pw[k*50 + lane] : 0.f;
    float4 a0 = *reinterpret_cast<const float4*>(&hl[tm][k*8]);
    float4 a1 = *reinterpret_cast<const float4*>(&hl[tm][k*8+4]);
    acc[0]+=a0.x*wv; acc[1]+=a0.y*wv; acc[2]+=a0.z*wv; acc[3]+=a0.w*wv;
    acc[4]+=a1.x*wv; acc[5]+=a1.y*wv; acc[6]+=a1.z*wv; acc[7]+=a1.w*wv;
  }
  if (act) {
    float bias = pb[lane];
    #pragma unroll
    for (int r = 0; r < 8; ++r) {
      float v = acc[r] + bias;
      float sp = fmaxf(v, 0.f) + log1pf(__expf(-fabsf(v)));
      out[(row0+r)*50 + lane] = sp;
    }
  }
}

extern "C" void kernel_launch(void* const* d_in, const int* in_sizes, int n_in,
                              void* d_out, int out_size, void* d_ws, size_t ws_size,
                              hipStream_t stream) {
  const float* x    = (const float*)d_in[0];
  const float* ew   = (const float*)d_in[1];
  const float* eb   = (const float*)d_in[2];
  const float* ln0g = (const float*)d_in[3];
  const float* ln0b = (const float*)d_in[4];
  const float* pw   = (const float*)d_in[5];
  const float* pb   = (const float*)d_in[6];
  float* out = (float*)d_out;

  size_t nBT  = (size_t)BB*TT*HH;   // 8.39M elems
  size_t nSum = (size_t)BB*NC*HH;   // 262144 elems
  unsigned short* h  = (unsigned short*)d_ws;
  unsigned*       ab = (unsigned*)(h + nBT);
  float* Asum  = (float*)(ab + nBT);
  float* Bsum  = Asum + nSum;
  float* carry = Bsum + nSum;
  unsigned short* wt = (unsigned short*)(carry + nSum);

  prep_kernel<<<384, 256, 0, stream>>>((const float*)d_in[7], (const float*)d_in[11],
                                       (const float*)d_in[15], wt);
  embed_kernel<<<(BB*TT)/32, 128, 0, stream>>>(x, ew, eb, ln0g, ln0b, h);

  for (int l = 0; l < 3; ++l) {
    const float* gb = (const float*)d_in[8 + 4*l];
    const float* lg = (const float*)d_in[9 + 4*l];
    const float* lb = (const float*)d_in[10 + 4*l];
    gru_mm_kernel<<<(BB*NC)/4, 256, 0, stream>>>(h, wt + (size_t)l*32768, gb, ab, Asum, Bsum);
    scan_kernel<<<BB, 128, 0, stream>>>(Asum, Bsum, carry);
    apply_kernel<<<(BB*NC)/4, 256, 0, stream>>>(ab, carry, lg, lb, h);
  }

  proj_kernel<<<(BB*TT)/32, 256, 0, stream>>>(h, pw, pb, out);
}

// Round 3
// 241.717 us; speedup vs baseline: 1.8556x; 1.2082x over previous
//
#include <hip/hip_runtime.h>
#include <math.h>

#define BB 8
#define TT 8192
#define XX 64
#define HH 128
#define CHUNK 32
#define NC (TT/CHUNK)

typedef __attribute__((ext_vector_type(8))) short short8;
typedef __attribute__((ext_vector_type(4))) float f32x4;

__device__ __forceinline__ float sigm(float x){ return 1.0f/(1.0f+__expf(-x)); }
__device__ __forceinline__ unsigned short f2bf(float f){
  unsigned u = __float_as_uint(f);
  return (unsigned short)((u + 0x7fffu + ((u>>16)&1u)) >> 16);
}
__device__ __forceinline__ float bf2f(unsigned b){ return __uint_as_float(b << 16); }

// P0: build all bf16 weight tables, pre-swizzled (byte ^= (col&7)<<4) so the MFMA
// kernels stage LDS linearly and read with the same XOR -> conflict-free ds_read_b128.
//  wt   [3][256][128] : gru W^T        (idx 0      .. 98303)
//  wt_e [128][64]     : embed W^T      (idx 98304  .. 106495)
//  wt_p [64][128]     : proj W^T, cols>=50 zero (idx 106496 .. 114687)
__global__ __launch_bounds__(256) void prep_kernel(
    const float* __restrict__ w1, const float* __restrict__ w2, const float* __restrict__ w3,
    const float* __restrict__ ew, const float* __restrict__ pw,
    unsigned short* __restrict__ wt, unsigned short* __restrict__ wt_e, unsigned short* __restrict__ wt_p)
{
  int idx = blockIdx.x*256 + threadIdx.x;
  if (idx < 98304) {
    int l = idx >> 15;
    int e = idx & 32767;
    int k = e >> 8;
    int col = e & 255;
    const float* w = (l==0) ? w1 : ((l==1) ? w2 : w3);
    float v = w[e];
    unsigned byte = ((unsigned)col*128u + (unsigned)k)*2u;
    byte ^= (unsigned)((col & 7) << 4);
    wt[(size_t)l*32768 + (byte >> 1)] = f2bf(v);
  } else if (idx < 106496) {
    int e = idx - 98304;          // col*64 + k
    int col = e >> 6, k = e & 63;
    float v = ew[k*HH + col];
    unsigned byte = ((unsigned)e*2u) ^ (unsigned)((col & 7) << 4);
    wt_e[byte >> 1] = f2bf(v);
  } else {
    int e = idx - 106496;         // col*128 + k
    int col = e >> 7, k = e & 127;
    float v = (col < 50) ? pw[k*50 + col] : 0.f;
    unsigned byte = ((unsigned)e*2u) ^ (unsigned)((col & 7) << 4);
    wt_p[byte >> 1] = f2bf(v);
  }
}

// K1: embed (64->128) MFMA + leaky_relu + LN0 -> h (bf16).
// Block = 4 waves, wave = 32 rows. x f32 converted to bf16 in-register.
__global__ __launch_bounds__(256) void embed_mfma_kernel(
    const float* __restrict__ x, const unsigned short* __restrict__ wt_e,
    const float* __restrict__ eb, const float* __restrict__ g, const float* __restrict__ be,
    unsigned short* __restrict__ hout)
{
  __shared__ short8 wlds[1024];   // 16 KB
  int tid = threadIdx.x;
  const short8* wsrc = (const short8*)wt_e;
  #pragma unroll
  for (int i = 0; i < 4; ++i) wlds[i*256 + tid] = wsrc[i*256 + tid];
  __syncthreads();

  int wid = tid >> 6, lane = tid & 63;
  int lr = lane & 15, lg = lane >> 4;
  int sx = (lane & 7) << 4;
  long row0 = (long)(blockIdx.x*4 + wid)*32;

  // A fragments: f32 -> bf16
  short8 af[2][2];
  #pragma unroll
  for (int m = 0; m < 2; ++m)
    #pragma unroll
    for (int s = 0; s < 2; ++s) {
      const float* xp = x + (row0 + m*16 + lr)*XX + s*32 + lg*8;
      float4 u0 = *(const float4*)xp;
      float4 u1 = *(const float4*)(xp + 4);
      short8 t;
      t[0]=f2bf(u0.x); t[1]=f2bf(u0.y); t[2]=f2bf(u0.z); t[3]=f2bf(u0.w);
      t[4]=f2bf(u1.x); t[5]=f2bf(u1.y); t[6]=f2bf(u1.z); t[7]=f2bf(u1.w);
      af[m][s] = t;
    }

  const char* wbase = (const char*)wlds;
  f32x4 acc[2][8];
  #pragma unroll
  for (int m = 0; m < 2; ++m)
    #pragma unroll
    for (int np = 0; np < 8; ++np) acc[m][np] = (f32x4){0.f,0.f,0.f,0.f};

  #pragma unroll
  for (int np = 0; np < 8; ++np) {
    int col = np*16 + lr;
    #pragma unroll
    for (int s = 0; s < 2; ++s) {
      short8 bh = *(const short8*)(wbase + ((col*128 + s*64 + lg*16) ^ sx));
      #pragma unroll
      for (int m = 0; m < 2; ++m)
        acc[m][np] = __builtin_amdgcn_mfma_f32_16x16x32_bf16(af[m][s], bh, acc[m][np], 0, 0, 0);
    }
  }

  float gamv[8], betv[8], biasv[8];
  #pragma unroll
  for (int np = 0; np < 8; ++np) {
    int col = np*16 + lr;
    gamv[np] = g[col]; betv[np] = be[col]; biasv[np] = eb[col];
  }

  #pragma unroll
  for (int m = 0; m < 2; ++m) {
    float s4[4], q4[4];
    #pragma unroll
    for (int r = 0; r < 4; ++r) { s4[r] = 0.f; q4[r] = 0.f; }
    #pragma unroll
    for (int np = 0; np < 8; ++np)
      #pragma unroll
      for (int r = 0; r < 4; ++r) {
        float v = acc[m][np][r] + biasv[np];
        v = v > 0.f ? v : 0.01f*v;
        acc[m][np][r] = v;
        s4[r] += v; q4[r] += v*v;
      }
    #pragma unroll
    for (int off = 1; off < 16; off <<= 1)
      #pragma unroll
      for (int r = 0; r < 4; ++r) {
        s4[r] += __shfl_xor(s4[r], off);
        q4[r] += __shfl_xor(q4[r], off);
      }
    #pragma unroll
    for (int r = 0; r < 4; ++r) {
      float mu = s4[r] * (1.f/128.f);
      float var = q4[r] * (1.f/128.f) - mu*mu;
      float rs = rsqrtf(var + 1e-5f);
      long row = row0 + m*16 + lg*4 + r;
      #pragma unroll
      for (int np = 0; np < 8; ++np)
        hout[row*HH + np*16 + lr] = f2bf((acc[m][np][r]-mu)*rs*gamv[np] + betv[np]);
    }
  }
}

// K2: MFMA minGRU matmul. Block = 4 waves, wave = 1 chunk (32 rows).
__global__ __launch_bounds__(256) void gru_mm_kernel(
    const unsigned short* __restrict__ h, const unsigned short* __restrict__ wt,
    const float* __restrict__ bias,
    unsigned* __restrict__ ab, float* __restrict__ Asum, float* __restrict__ Bsum)
{
  __shared__ short8 wlds[4096];   // 64 KB
  int tid = threadIdx.x;
  const short8* wsrc = (const short8*)wt;
  #pragma unroll
  for (int i = 0; i < 16; ++i) wlds[i*256 + tid] = wsrc[i*256 + tid];
  __syncthreads();

  int wid = tid >> 6, lane = tid & 63;
  int chunk = blockIdx.x*4 + wid;
  int b = chunk >> 8;
  int c = chunk & 255;
  long row0 = (long)b*TT + (long)c*CHUNK;
  int lr = lane & 15, lg = lane >> 4;
  int sx = (lane & 7) << 4;

  short8 af[2][4];
  #pragma unroll
  for (int m = 0; m < 2; ++m)
    #pragma unroll
    for (int s = 0; s < 4; ++s)
      af[m][s] = *(const short8*)(h + (row0 + m*16 + lr)*HH + s*32 + lg*8);

  const char* wbase = (const char*)wlds;
  #pragma unroll 2
  for (int np = 0; np < 8; ++np) {
    f32x4 acch[2], accg[2];
    #pragma unroll
    for (int m = 0; m < 2; ++m) { acch[m] = (f32x4){0.f,0.f,0.f,0.f}; accg[m] = (f32x4){0.f,0.f,0.f,0.f}; }
    int rh = np*16 + lr;
    int rg = rh + 128;
    #pragma unroll
    for (int s = 0; s < 4; ++s) {
      short8 bh = *(const short8*)(wbase + ((rh*256 + s*64 + lg*16) ^ sx));
      short8 bg = *(const short8*)(wbase + ((rg*256 + s*64 + lg*16) ^ sx));
      #pragma unroll
      for (int m = 0; m < 2; ++m) {
        acch[m] = __builtin_amdgcn_mfma_f32_16x16x32_bf16(af[m][s], bh, acch[m], 0, 0, 0);
        accg[m] = __builtin_amdgcn_mfma_f32_16x16x32_bf16(af[m][s], bg, accg[m], 0, 0, 0);
      }
    }
    int col = np*16 + lr;
    float bh0 = bias[col], bg0 = bias[HH + col];
    float At[2], Bt[2];
    #pragma unroll
    for (int m = 0; m < 2; ++m) {
      float A4 = 1.f, B4 = 0.f;
      #pragma unroll
      for (int r = 0; r < 4; ++r) {
        float hid = acch[m][r] + bh0;
        float z = sigm(accg[m][r] + bg0);
        float gv = hid >= 0.f ? hid + 0.5f : sigm(hid);
        float av = 1.f - z, bv = z*gv;
        size_t grow = (size_t)(row0 + m*16 + lg*4 + r);
        ab[grow*HH + col] = (unsigned)f2bf(av) | ((unsigned)f2bf(bv) << 16);
        A4 *= av; B4 = av*B4 + bv;
      }
      #pragma unroll
      for (int off = 1; off < 4; off <<= 1) {
        float pa = __shfl_up(A4, off*16);
        float pb = __shfl_up(B4, off*16);
        float na = pa*A4, nb = A4*pb + B4;
        if (lg >= off) { A4 = na; B4 = nb; }
      }
      At[m] = __shfl(A4, 48 + lr);
      Bt[m] = __shfl(B4, 48 + lr);
    }
    if (lane < 16) {
      float Ac = At[0]*At[1];
      float Bc = At[1]*Bt[0] + Bt[1];
      int sidx = chunk*HH + col;
      Asum[sidx] = Ac;
      Bsum[sidx] = Bc;
    }
  }
}

// K3: serial scan over 256 chunk summaries per (b,d)
__global__ __launch_bounds__(128) void scan_kernel(
    const float* __restrict__ Asum, const float* __restrict__ Bsum, float* __restrict__ carry)
{
  int b = blockIdx.x; int d = threadIdx.x;
  float run = 0.f;
  #pragma unroll 4
  for (int c = 0; c < NC; ++c) {
    int idx = (b*NC + c)*HH + d;
    carry[idx] = run;
    run = Asum[idx]*run + Bsum[idx];
  }
}

// K4: apply recurrence + fused LN -> h (bf16). Block = 4 waves, wave = 1 chunk.
__global__ __launch_bounds__(256) void apply_kernel(
    const unsigned* __restrict__ ab, const float* __restrict__ carry,
    const float* __restrict__ g, const float* __restrict__ be,
    unsigned short* __restrict__ hout)
{
  int tid = threadIdx.x, wid = tid >> 6, lane = tid & 63;
  int chunk = blockIdx.x*4 + wid;
  float2 hc = ((const float2*)(carry + (size_t)chunk*HH))[lane];
  float2 gam = ((const float2*)g)[lane];
  float2 bet = ((const float2*)be)[lane];
  size_t rowbase = (size_t)chunk*CHUNK;
  for (int gq = 0; gq < 4; ++gq) {
    uint2 v[8];
    #pragma unroll
    for (int j = 0; j < 8; ++j)
      v[j] = ((const uint2*)(ab + (rowbase + gq*8 + j)*HH))[lane];
    #pragma unroll
    for (int j = 0; j < 8; ++j) {
      float ax = bf2f(v[j].x & 0xffffu), bx = bf2f(v[j].x >> 16);
      float ay = bf2f(v[j].y & 0xffffu), by = bf2f(v[j].y >> 16);
      hc.x = ax*hc.x + bx;
      hc.y = ay*hc.y + by;
      float s = hc.x + hc.y, q = hc.x*hc.x + hc.y*hc.y;
      #pragma unroll
      for (int m = 1; m < 64; m <<= 1) { s += __shfl_xor(s, m); q += __shfl_xor(q, m); }
      float mu = s * (1.f/128.f);
      float var = q * (1.f/128.f) - mu*mu;
      float rs = rsqrtf(var + 1e-5f);
      unsigned o = (unsigned)f2bf((hc.x-mu)*rs*gam.x + bet.x)
                 | ((unsigned)f2bf((hc.y-mu)*rs*gam.y + bet.y) << 16);
      ((unsigned*)hout)[(rowbase + gq*8 + j)*64 + lane] = o;
    }
  }
}

// K5: proj (128->50 padded to 64) MFMA + softplus -> out f32.
__global__ __launch_bounds__(256) void proj_mfma_kernel(
    const unsigned short* __restrict__ hin, const unsigned short* __restrict__ wt_p,
    const float* __restrict__ pb, float* __restrict__ out)
{
  __shared__ short8 wlds[1024];   // 16 KB
  int tid = threadIdx.x;
  const short8* wsrc = (const short8*)wt_p;
  #pragma unroll
  for (int i = 0; i < 4; ++i) wlds[i*256 + tid] = wsrc[i*256 + tid];
  __syncthreads();

  int wid = tid >> 6, lane = tid & 63;
  int lr = lane & 15, lg = lane >> 4;
  int sx = (lane & 7) << 4;
  long row0 = (long)(blockIdx.x*4 + wid)*32;

  short8 af[2][4];
  #pragma unroll
  for (int m = 0; m < 2; ++m)
    #pragma unroll
    for (int s = 0; s < 4; ++s)
      af[m][s] = *(const short8*)(hin + (row0 + m*16 + lr)*HH + s*32 + lg*8);

  const char* wbase = (const char*)wlds;
  f32x4 acc[2][4];
  #pragma unroll
  for (int m = 0; m < 2; ++m)
    #pragma unroll
    for (int np = 0; np < 4; ++np) acc[m][np] = (f32x4){0.f,0.f,0.f,0.f};

  #pragma unroll
  for (int np = 0; np < 4; ++np) {
    int col = np*16 + lr;
    #pragma unroll
    for (int s = 0; s < 4; ++s) {
      short8 bh = *(const short8*)(wbase + ((col*256 + s*64 + lg*16) ^ sx));
      #pragma unroll
      for (int m = 0; m < 2; ++m)
        acc[m][np] = __builtin_amdgcn_mfma_f32_16x16x32_bf16(af[m][s], bh, acc[m][np], 0, 0, 0);
    }
  }

  #pragma unroll
  for (int np = 0; np < 4; ++np) {
    int col = np*16 + lr;
    bool act = col < 50;
    float bias = act ? pb[col] : 0.f;
    #pragma unroll
    for (int m = 0; m < 2; ++m)
      #pragma unroll
      for (int r = 0; r < 4; ++r) {
        float v = acc[m][np][r] + bias;
        float sp = fmaxf(v, 0.f) + log1pf(__expf(-fabsf(v)));
        if (act) out[(row0 + m*16 + lg*4 + r)*50 + col] = sp;
      }
  }
}

extern "C" void kernel_launch(void* const* d_in, const int* in_sizes, int n_in,
                              void* d_out, int out_size, void* d_ws, size_t ws_size,
                              hipStream_t stream) {
  const float* x    = (const float*)d_in[0];
  const float* ew   = (const float*)d_in[1];
  const float* eb   = (const float*)d_in[2];
  const float* ln0g = (const float*)d_in[3];
  const float* ln0b = (const float*)d_in[4];
  const float* pw   = (const float*)d_in[5];
  const float* pb   = (const float*)d_in[6];
  float* out = (float*)d_out;

  size_t nBT  = (size_t)BB*TT*HH;   // 8.39M elems
  size_t nSum = (size_t)BB*NC*HH;   // 262144 elems
  unsigned short* h  = (unsigned short*)d_ws;
  unsigned*       ab = (unsigned*)(h + nBT);
  float* Asum  = (float*)(ab + nBT);
  float* Bsum  = Asum + nSum;
  float* carry = Bsum + nSum;
  unsigned short* wt   = (unsigned short*)(carry + nSum);
  unsigned short* wt_e = wt + 3*32768;
  unsigned short* wt_p = wt_e + 8192;

  prep_kernel<<<448, 256, 0, stream>>>((const float*)d_in[7], (const float*)d_in[11],
                                       (const float*)d_in[15], ew, pw, wt, wt_e, wt_p);
  embed_mfma_kernel<<<(BB*TT)/128, 256, 0, stream>>>(x, wt_e, eb, ln0g, ln0b, h);

  for (int l = 0; l < 3; ++l) {
    const float* gb = (const float*)d_in[8 + 4*l];
    const float* lg = (const float*)d_in[9 + 4*l];
    const float* lb = (const float*)d_in[10 + 4*l];
    gru_mm_kernel<<<(BB*NC)/4, 256, 0, stream>>>(h, wt + (size_t)l*32768, gb, ab, Asum, Bsum);
    scan_kernel<<<BB, 128, 0, stream>>>(Asum, Bsum, carry);
    apply_kernel<<<(BB*NC)/4, 256, 0, stream>>>(ab, carry, lg, lb, h);
  }

  proj_mfma_kernel<<<(BB*TT)/128, 256, 0, stream>>>(h, pw != nullptr ? wt_p : wt_p, pb, out);
}